// Round 7
// baseline (283.923 us; speedup 1.0000x reference)
//
#include <hip/hip_runtime.h>

#define NEGF (-3.402823466e38f)
#define LOG2E 1.4426950408889634f

constexpr int H  = 8,  DH = 32, DN = 256, DE = 128;
constexpr int RR = 128, WW = 256;
constexpr int MROWS = RR * WW;     // 32768 token rows

typedef __attribute__((ext_vector_type(8))) short bf16x8;
typedef __attribute__((ext_vector_type(4))) short bf16x4;
typedef __attribute__((ext_vector_type(4))) float f32x4;
typedef __attribute__((ext_vector_type(2))) int i32x2;

__device__ __forceinline__ float b2f(short s) {
  unsigned u = ((unsigned)(unsigned short)s) << 16;
  return __builtin_bit_cast(float, u);
}
__device__ __forceinline__ short f2b(float f) {   // round-to-nearest-even
  unsigned u = __builtin_bit_cast(unsigned, f);
  unsigned r = (u + 0x7fffu + ((u >> 16) & 1u)) >> 16;
  return (short)r;
}
__device__ __forceinline__ float wred(float v) {
#pragma unroll
  for (int off = 32; off > 0; off >>= 1) v += __shfl_xor(v, off, 64);
  return v;
}

// ---------------- K1: LayerNorm(x) -> xnb (bf16) [32768 x 256] ----------------
__global__ __launch_bounds__(256) void k_ln_x(const float* __restrict__ x,
                                              const float* __restrict__ g,
                                              const float* __restrict__ b,
                                              short* __restrict__ xnb) {
  const int wave = threadIdx.x >> 6, lane = threadIdx.x & 63;
  const int row = (blockIdx.x << 2) + wave;
  const float4 v = ((const float4*)(x + (size_t)row * DN))[lane];
  float s  = v.x + v.y + v.z + v.w;
  float s2 = v.x*v.x + v.y*v.y + v.z*v.z + v.w*v.w;
  s = wred(s); s2 = wred(s2);
  const float mu = s * (1.f / DN);
  const float rs = rsqrtf(s2 * (1.f / DN) - mu * mu + 1e-5f);
  const float4 gg = ((const float4*)g)[lane];
  const float4 bb = ((const float4*)b)[lane];
  bf16x4 o;
  o[0] = f2b((v.x - mu) * rs * gg.x + bb.x);
  o[1] = f2b((v.y - mu) * rs * gg.y + bb.y);
  o[2] = f2b((v.z - mu) * rs * gg.z + bb.z);
  o[3] = f2b((v.w - mu) * rs * gg.w + bb.w);
  ((bf16x4*)(xnb + (size_t)row * DN))[lane] = o;
}

// ---- K1b: cast+transpose weights -> wt bf16: [0,262144) = WqkvgT[1024][256],
// ----      [262144,327680) = WoT[256][256]
__global__ __launch_bounds__(256) void k_prep(const float* __restrict__ Wq,
                                              const float* __restrict__ Wkv,
                                              const float* __restrict__ Wg,
                                              const float* __restrict__ Wo,
                                              short* __restrict__ wt) {
  const int idx = blockIdx.x * 256 + threadIdx.x;
  if (idx < 262144) {
    const int n = idx >> 8, k = idx & 255;
    float v;
    if (n < 256)      v = Wq[k * 256 + n];
    else if (n < 768) v = Wkv[k * 512 + (n - 256)];   // k cols 0-255, v cols 256-511
    else              v = Wg[k * 256 + (n - 768)];
    wt[idx] = f2b(v);
  } else {
    const int m = idx - 262144;
    const int n = m >> 8, k = m & 255;
    wt[idx] = f2b(Wo[k * 256 + n]);
  }
}

// ------- K2: LayerNorm(edges)@W_edge -> bias2[h][j>>2][q][j&3] (f32 * log2e) -------
__global__ __launch_bounds__(256) void k_bias(const float* __restrict__ edges,
                                              const int* __restrict__ emask,
                                              const float* __restrict__ g,
                                              const float* __restrict__ b,
                                              const float* __restrict__ We,
                                              float* __restrict__ bias2) {
  const int wave = threadIdx.x >> 6, lane = threadIdx.x & 63;
  const int p = (blockIdx.x << 2) + wave;   // p = j*WW + i
  const int i = p & (WW - 1), j = p >> 8;
  const float2 e = ((const float2*)(edges + (size_t)(i * WW + j) * DE))[lane];
  float s = e.x + e.y, s2 = e.x*e.x + e.y*e.y;
  s = wred(s); s2 = wred(s2);
  const float mu = s * (1.f / DE);
  const float rs = rsqrtf(s2 * (1.f / DE) - mu * mu + 1e-5f);
  const float2 gg = ((const float2*)g)[lane];
  const float2 bb = ((const float2*)b)[lane];
  const float n0 = (e.x - mu) * rs * gg.x + bb.x;
  const float n1 = (e.y - mu) * rs * gg.y + bb.y;
  const float* w0 = We + (lane * 2) * H;
  float acc[H];
#pragma unroll
  for (int h = 0; h < H; ++h) acc[h] = n0 * w0[h] + n1 * w0[H + h];
#pragma unroll
  for (int off = 32; off > 0; off >>= 1)
#pragma unroll
    for (int h = 0; h < H; ++h) acc[h] += __shfl_xor(acc[h], off, 64);
  if (lane == 0) {
    const int em = emask[i * WW + j];
#pragma unroll
    for (int h = 0; h < H; ++h)
      bias2[(size_t)((h << 6) + (j >> 2)) * 1024 + (i << 2) + (j & 3)]
          = em ? acc[h] * LOG2E : NEGF;    // pre-scaled for exp2-domain softmax
  }
}

// ------- K3/K5: bf16 MFMA GEMM, C[M,N] = A[M,256] @ Bt[N,256]^T -------
// B-stationary: whole 128x256 B-tile in LDS (XOR-swizzled, staged once),
// A-fragments streamed from global. No barriers in the K-loop.
template<int N, int EPI>
__global__ __launch_bounds__(256) void k_gemm(const short* __restrict__ A,
                                              const short* __restrict__ Bt,
                                              const float* __restrict__ bias,
                                              void* __restrict__ Cout) {
  __shared__ short Bs[128 * 256];   // 64 KB
  const int tid = threadIdx.x;
  const int w = tid >> 6, lane = tid & 63;
  const int g = lane >> 4, c = lane & 15;
  constexpr int nb = N / 128;
  const int bm = (int)(blockIdx.x / nb) * 128;   // consecutive blocks share bm -> A L2 reuse
  const int bn = (int)(blockIdx.x % nb) * 128;

  // stage B 64KB linear; source pre-swizzled so read-side XOR lands right (rule 21)
  const char* Bt_b = (const char*)(Bt + (size_t)bn * 256);
#pragma unroll
  for (int q = 0; q < 16; ++q) {
    const int o = (q * 256 + tid) * 16;                  // LDS byte offset
    const int osw = o ^ ((((o >> 9) & 7)) << 4);         // involution within 512B row
    __builtin_amdgcn_global_load_lds(
        (const __attribute__((address_space(1))) void*)(Bt_b + osw),
        (__attribute__((address_space(3))) void*)((__attribute__((address_space(3))) char*)Bs + o),
        16, 0, 0);
  }
  asm volatile("s_waitcnt vmcnt(0)" ::: "memory");
  __syncthreads();

  const int m0 = bm + (w << 5);
  f32x4 acc[2][8] = {};
  const char* Bs_b = (const char*)Bs;
#pragma unroll
  for (int ks = 0; ks < 8; ++ks) {
    bf16x8 af[2];
#pragma unroll
    for (int mi = 0; mi < 2; ++mi)
      af[mi] = *(const bf16x8*)(A + (size_t)(m0 + (mi << 4) + c) * 256 + (ks << 5) + (g << 3));
    bf16x8 bfr[8];
#pragma unroll
    for (int ni = 0; ni < 8; ++ni) {
      const int L = ((ni << 4) + c) * 512 + (ks << 6) + (g << 4);
      bfr[ni] = *(const bf16x8*)(Bs_b + (L ^ ((c & 7) << 4)));
    }
#pragma unroll
    for (int mi = 0; mi < 2; ++mi)
#pragma unroll
      for (int ni = 0; ni < 8; ++ni)
        acc[mi][ni] = __builtin_amdgcn_mfma_f32_16x16x32_bf16(af[mi], bfr[ni], acc[mi][ni], 0, 0, 0);
  }

  const int r0 = bm + (w << 5) + (g << 2);
  const int c0 = bn + c;
#pragma unroll
  for (int mi = 0; mi < 2; ++mi)
#pragma unroll
    for (int ni = 0; ni < 8; ++ni) {
      const int col = c0 + (ni << 4);
      if (EPI == 0) {
        short* C = (short*)Cout;
        const bool gate = (bn + (ni << 4)) >= 768;
        const float bgv = gate ? bias[col - 768] : 0.f;
#pragma unroll
        for (int jj = 0; jj < 4; ++jj) {
          float v = acc[mi][ni][jj];
          if (gate) v = 1.f / (1.f + __expf(-(v + bgv)));
          C[(size_t)(r0 + (mi << 4) + jj) * N + col] = f2b(v);
        }
      } else {
        float* C = (float*)Cout;
        const float bv = bias[col];
#pragma unroll
        for (int jj = 0; jj < 4; ++jj)
          C[(size_t)(r0 + (mi << 4) + jj) * N + col] = acc[mi][ni][jj] + bv;
      }
    }
}

// ------- K4: MFMA flash attention per (r,h), exp2-domain softmax -------
__global__ __launch_bounds__(256) void k_attn(const short* __restrict__ qkvg,
                                              const float* __restrict__ bias2,
                                              const int* __restrict__ mask,
                                              short* __restrict__ aout) {
  __shared__ short K_lds[256 * 40];            // 20 KB, [j][40] padded
  __shared__ alignas(16) short VS[8192];       // 16 KB: [dt][jq][t=j&3][c=d&15]
  __shared__ float jm_lds[256];                // additive row-mask: 0 or NEGF
  const int r = blockIdx.x >> 3, h = blockIdx.x & 7;
  const int tid = threadIdx.x;
  const int w = tid >> 6, lane = tid & 63;
  const int g = lane >> 4, c = lane & 15;
  const size_t rowbase = (size_t)r * WW;

  // ---- stage K, V (subtiled), mask ----
  {
    const int jr = tid >> 2, ch = (tid & 3) << 3;
    const int dt = ch >> 4, cc = ch & 15;
#pragma unroll
    for (int p = 0; p < 4; ++p) {
      const int j = (p << 6) + jr;
      const short* src = qkvg + (rowbase + j) * 1024 + 256 + h * 32 + ch;
      *(bf16x8*)&K_lds[j * 40 + ch] = *(const bf16x8*)src;
      *(bf16x8*)&VS[(dt << 12) + ((j >> 2) << 6) + ((j & 3) << 4) + cc] =
          *(const bf16x8*)(src + 256);
    }
    jm_lds[tid] = mask[r * WW + tid] ? 0.f : NEGF;
  }
  __syncthreads();

  // ---- per-wave state: q rows [64w, 64w+64) ----
  const int q0 = (w << 6);
  bf16x8 qf[4];
  float qm[4];
#pragma unroll
  for (int qt = 0; qt < 4; ++qt) {
    qf[qt] = *(const bf16x8*)(qkvg + (rowbase + q0 + (qt << 4) + c) * 1024 + h * 32 + (g << 3));
    qm[qt] = jm_lds[q0 + (qt << 4) + c];
  }
  float m[4] = {NEGF, NEGF, NEGF, NEGF}, l[4] = {};
  f32x4 O[4][2] = {};
  const float scale2 = 0.2550541611f;   // 32^-0.5 * log2(e)
  const float* bh = bias2 + ((size_t)h << 16);
  // true LDS byte offset (AS(3) cast — NOT the flat aperture address)
  const unsigned vs_base =
      (unsigned)(uintptr_t)(__attribute__((address_space(3))) char*)VS;

#pragma unroll 2
  for (int jb = 0; jb < WW; jb += 32) {
    // V transpose-reads issued early (T10); consumed after lgkmcnt below.
    // NOTE: 4 SEPARATE asm statements — in a single multi-instruction block the
    // non-earlyclobber outputs could alias the shared address register (round-6
    // accuracy bug). Separate statements keep `va` live across all four, so no
    // output can be allocated to it.
    i32x2 vlo0, vhi0, vlo1, vhi1;
    const unsigned va = vs_base + ((unsigned)(jb >> 2) << 7) + lane * 8;
    asm volatile("ds_read_b64_tr_b16 %0, %1 offset:0"    : "=v"(vlo0) : "v"(va));
    asm volatile("ds_read_b64_tr_b16 %0, %1 offset:512"  : "=v"(vhi0) : "v"(va));
    asm volatile("ds_read_b64_tr_b16 %0, %1 offset:8192" : "=v"(vlo1) : "v"(va));
    asm volatile("ds_read_b64_tr_b16 %0, %1 offset:8704" : "=v"(vhi1) : "v"(va));
    const bf16x8 kf0 = *(const bf16x8*)&K_lds[(jb + c) * 40 + (g << 3)];
    const bf16x8 kf1 = *(const bf16x8*)&K_lds[(jb + 16 + c) * 40 + (g << 3)];
    const f32x4 jm0 = *(const f32x4*)&jm_lds[jb + (g << 2)];
    const f32x4 jm1 = *(const f32x4*)&jm_lds[jb + 16 + (g << 2)];
    f32x4 bv[4][2];
#pragma unroll
    for (int qt = 0; qt < 4; ++qt) {
      const int qq = (q0 + (qt << 4) + c) << 2;
      bv[qt][0] = *(const f32x4*)(bh + (size_t)((jb >> 2) + g) * 1024 + qq);
      bv[qt][1] = *(const f32x4*)(bh + (size_t)((jb >> 2) + 4 + g) * 1024 + qq);
    }
    f32x4 s[4][2];
    float pmax[4];
#pragma unroll
    for (int qt = 0; qt < 4; ++qt) {
      const f32x4 z = {0.f, 0.f, 0.f, 0.f};
      s[qt][0] = __builtin_amdgcn_mfma_f32_16x16x32_bf16(kf0, qf[qt], z, 0, 0, 0);
      s[qt][1] = __builtin_amdgcn_mfma_f32_16x16x32_bf16(kf1, qf[qt], z, 0, 0, 0);
      float pm = NEGF;
#pragma unroll
      for (int rr = 0; rr < 4; ++rr) {
        float t0 = fmaxf(fmaf(s[qt][0][rr], scale2, bv[qt][0][rr]) + jm0[rr] + qm[qt], NEGF);
        float t1 = fmaxf(fmaf(s[qt][1][rr], scale2, bv[qt][1][rr]) + jm1[rr] + qm[qt], NEGF);
        s[qt][0][rr] = t0; s[qt][1][rr] = t1;
        pm = fmaxf(pm, fmaxf(t0, t1));
      }
      pm = fmaxf(pm, __shfl_xor(pm, 16, 64));
      pm = fmaxf(pm, __shfl_xor(pm, 32, 64));
      pmax[qt] = pm;
    }
    // defer-max (T13): threshold 8 nats = 11.5416 in log2 domain
    int need = 0;
#pragma unroll
    for (int qt = 0; qt < 4; ++qt) need |= (pmax[qt] > m[qt] + 11.5416f);
    if (__any(need)) {
      float fr[4];
#pragma unroll
      for (int qt = 0; qt < 4; ++qt) {
        const float mn = fmaxf(m[qt], pmax[qt]);
        fr[qt] = exp2f(m[qt] - mn);
        m[qt] = mn; l[qt] *= fr[qt];
      }
#pragma unroll
      for (int qt = 0; qt < 4; ++qt)
#pragma unroll
        for (int rr = 0; rr < 4; ++rr) {
          const float fb = __shfl(fr[qt], (g << 2) | rr, 64);
          O[qt][0][rr] *= fb; O[qt][1][rr] *= fb;
        }
    }
    // exp2, l-accumulate, pack P (scalar f2b)
    bf16x8 pa[4];
#pragma unroll
    for (int qt = 0; qt < 4; ++qt) {
      float sum = 0.f;
#pragma unroll
      for (int rr = 0; rr < 4; ++rr) {
        const float e0 = exp2f(s[qt][0][rr] - m[qt]);
        const float e1 = exp2f(s[qt][1][rr] - m[qt]);
        sum += e0 + e1;
        pa[qt][rr] = f2b(e0);
        pa[qt][rr + 4] = f2b(e1);
      }
      sum += __shfl_xor(sum, 16, 64);
      sum += __shfl_xor(sum, 32, 64);
      l[qt] += sum;
    }
    // consume V tr-reads (rule 18: lgkmcnt + sched_barrier before MFMA use)
    asm volatile("s_waitcnt lgkmcnt(0)" ::: "memory");
    __builtin_amdgcn_sched_barrier(0);
    const bf16x4 l0 = __builtin_bit_cast(bf16x4, vlo0), h0 = __builtin_bit_cast(bf16x4, vhi0);
    const bf16x4 l1 = __builtin_bit_cast(bf16x4, vlo1), h1 = __builtin_bit_cast(bf16x4, vhi1);
    const bf16x8 vf0 = __builtin_shufflevector(l0, h0, 0, 1, 2, 3, 4, 5, 6, 7);
    const bf16x8 vf1 = __builtin_shufflevector(l1, h1, 0, 1, 2, 3, 4, 5, 6, 7);
#pragma unroll
    for (int qt = 0; qt < 4; ++qt) {
      O[qt][0] = __builtin_amdgcn_mfma_f32_16x16x32_bf16(pa[qt], vf0, O[qt][0], 0, 0, 0);
      O[qt][1] = __builtin_amdgcn_mfma_f32_16x16x32_bf16(pa[qt], vf1, O[qt][1], 0, 0, 0);
    }
  }

  // ---- epilogue: O * (1/l) * gate -> aout ----
  float inv[4];
#pragma unroll
  for (int qt = 0; qt < 4; ++qt) inv[qt] = 1.f / l[qt];
#pragma unroll
  for (int qt = 0; qt < 4; ++qt)
#pragma unroll
    for (int rr = 0; rr < 4; ++rr) {
      const float iv = __shfl(inv[qt], (g << 2) | rr, 64);
      const size_t row = rowbase + q0 + (qt << 4) + (g << 2) + rr;
#pragma unroll
      for (int dt = 0; dt < 2; ++dt) {
        const int d = (dt << 4) + c;
        const float gate = b2f(qkvg[row * 1024 + 768 + h * 32 + d]);
        aout[row * 256 + h * 32 + d] = f2b(O[qt][dt][rr] * iv * gate);
      }
    }
}

extern "C" void kernel_launch(void* const* d_in, const int* in_sizes, int n_in,
                              void* d_out, int out_size, void* d_ws, size_t ws_size,
                              hipStream_t stream) {
  const float* x      = (const float*)d_in[0];
  const float* edges  = (const float*)d_in[1];
  const int*   mask   = (const int*)d_in[2];
  const int*   emask  = (const int*)d_in[3];
  const float* ln_g   = (const float*)d_in[4];
  const float* ln_b   = (const float*)d_in[5];
  const float* lne_g  = (const float*)d_in[6];
  const float* lne_b  = (const float*)d_in[7];
  const float* W_edge = (const float*)d_in[8];
  const float* Wq     = (const float*)d_in[9];
  const float* Wkv    = (const float*)d_in[10];
  const float* Wg     = (const float*)d_in[11];
  const float* bg     = (const float*)d_in[12];
  const float* Wo     = (const float*)d_in[13];
  const float* bo     = (const float*)d_in[14];
  float* out = (float*)d_out;

  // ws layout (bytes): qkvgb 67,108,864 | xnb 16,777,216 | aoutb 16,777,216 |
  //                    wt 655,360 | bias2 2,097,152   => ~98.6 MB total
  char*  ws    = (char*)d_ws;
  short* qkvgb = (short*)ws;
  short* xnb   = (short*)(ws + 67108864);
  short* aoutb = (short*)(ws + 67108864 + 16777216);
  short* wt    = (short*)(ws + 100663296);
  float* bias2 = (float*)(ws + 101318656);

  k_ln_x<<<MROWS / 4, 256, 0, stream>>>(x, ln_g, ln_b, xnb);
  k_prep<<<1280, 256, 0, stream>>>(Wq, Wkv, Wg, Wo, wt);
  k_bias<<<(WW * WW) / 4, 256, 0, stream>>>(edges, emask, lne_g, lne_b, W_edge, bias2);
  k_gemm<1024, 0><<<256 * 8, 256, 0, stream>>>(xnb, wt, bg, (void*)qkvgb);
  k_attn<<<RR * H, 256, 0, stream>>>(qkvgb, bias2, mask, aoutb);
  k_gemm<256, 1><<<256 * 2, 256, 0, stream>>>(aoutb, wt + 262144, bo, (void*)out);
}